// Round 2
// baseline (1101.639 us; speedup 1.0000x reference)
//
#include <hip/hip_runtime.h>
#include <stdint.h>

#define HD 2048
#define NTOK 4096
#define NROUTED 7
#define NEXP 8
#define ROWS_ROUTED 8192   // 2*NTOK (top-2, exact)
#define ROWS_TOTAL 12288   // + shared 4096
#define ROWS_PAD 12416     // +128 slack for tile overshoot

typedef __attribute__((ext_vector_type(8))) __bf16 bf16x8;
typedef __attribute__((ext_vector_type(4))) float f32x4;
typedef __attribute__((ext_vector_type(8))) unsigned short u16x8;

__device__ __forceinline__ float bf2f(unsigned short h) {
  union { unsigned int u; float f; } x; x.u = ((unsigned int)h) << 16; return x.f;
}
__device__ __forceinline__ unsigned short f2bf(float f) {
  union { float f; unsigned int u; } x; x.f = f;
  unsigned int r = x.u + 0x7fffu + ((x.u >> 16) & 1u);   // RNE
  return (unsigned short)(r >> 16);
}

// ---- async global->LDS, 16B/lane. LDS dest is wave-uniform base + lane*16.
__device__ __forceinline__ void async16(const void* g, void* l) {
  __builtin_amdgcn_global_load_lds(
      (__attribute__((address_space(1))) const void*)(uintptr_t)g,
      (__attribute__((address_space(3))) void*)(unsigned int)(uintptr_t)l,
      16, 0, 0);
}

// ---------------- elementwise fp32 -> bf16 ----------------
__global__ __launch_bounds__(256) void k_convert_bf16(const float* __restrict__ in,
                                                      unsigned short* __restrict__ out, int n) {
  int i = (blockIdx.x * 256 + threadIdx.x) * 4;
  if (i >= n) return;
  float4 v = *(const float4*)(in + i);
  ushort4 o; o.x = f2bf(v.x); o.y = f2bf(v.y); o.z = f2bf(v.z); o.w = f2bf(v.w);
  *(ushort4*)(out + i) = o;
}

// ---------------- transpose+convert, 64x64 tile, vectorized both sides
// z = 0..6: routed matrix z from Wr_; z = 7: shared matrix from Ws_.
// in [2048][2048] f32 -> out[z] [2048][2048] bf16 = in^T
__global__ __launch_bounds__(256) void k_transpose8(const float* __restrict__ Wr_,
                                                    const float* __restrict__ Ws_,
                                                    unsigned short* __restrict__ out) {
  __shared__ float tile[64][65];
  const size_t bs = (size_t)HD * HD;
  int z = blockIdx.z;
  const float* in = (z < NROUTED) ? (Wr_ + (size_t)z * bs) : Ws_;
  unsigned short* dst = out + (size_t)z * bs;
  const int t = threadIdx.x;
  const int r0 = blockIdx.y * 64, c0 = blockIdx.x * 64;
  const int lr = t >> 4;             // 0..15
  const int lc = (t & 15) * 4;       // 0..60
  #pragma unroll
  for (int p = 0; p < 4; p++) {
    int row = p * 16 + lr;
    float4 v = *(const float4*)(in + (size_t)(r0 + row) * HD + c0 + lc);
    tile[row][lc] = v.x; tile[row][lc+1] = v.y; tile[row][lc+2] = v.z; tile[row][lc+3] = v.w;
  }
  __syncthreads();
  #pragma unroll
  for (int p = 0; p < 4; p++) {
    int oc = p * 16 + lr;            // output row = c0+oc (a column of in)
    ushort4 o;
    o.x = f2bf(tile[lc+0][oc]);
    o.y = f2bf(tile[lc+1][oc]);
    o.z = f2bf(tile[lc+2][oc]);
    o.w = f2bf(tile[lc+3][oc]);
    *(ushort4*)(dst + (size_t)(c0 + oc) * HD + r0 + lc) = o;
  }
}

// ---------------- router: gate = x@Wr + br; top-2 on gate+gate_bias; softmax of selected logits
// ctrl layout: [0..7]=counts, [8..15]=offsets, [16..23]=cursors
__global__ __launch_bounds__(256) void k_router(const float* __restrict__ x, const float* __restrict__ Wr,
                                                const float* __restrict__ br, const float* __restrict__ gbias,
                                                int* __restrict__ ids, float* __restrict__ wts,
                                                int* __restrict__ ctrl) {
  int lane = threadIdx.x & 63, wid = threadIdx.x >> 6;
  int t = blockIdx.x * 4 + wid;
  const float* xr = x + (size_t)t * HD;
  float acc[NROUTED];
  #pragma unroll
  for (int e = 0; e < NROUTED; e++) acc[e] = 0.f;
  for (int k = lane; k < HD; k += 64) {
    float xv = xr[k];
    const float* wrow = Wr + k * NROUTED;
    #pragma unroll
    for (int e = 0; e < NROUTED; e++) acc[e] += xv * wrow[e];
  }
  #pragma unroll
  for (int e = 0; e < NROUTED; e++) {
    #pragma unroll
    for (int off = 32; off > 0; off >>= 1) acc[e] += __shfl_down(acc[e], off);
  }
  if (lane == 0) {
    float lg[NROUTED], bg[NROUTED];
    #pragma unroll
    for (int e = 0; e < NROUTED; e++) { lg[e] = acc[e] + br[e]; bg[e] = lg[e] + gbias[e]; }
    int i1 = 0;
    #pragma unroll
    for (int e = 1; e < NROUTED; e++) if (bg[e] > bg[i1]) i1 = e;   // ties -> lowest idx
    int i2 = (i1 == 0) ? 1 : 0;
    #pragma unroll
    for (int e = 0; e < NROUTED; e++) if (e != i1 && bg[e] > bg[i2]) i2 = e;
    float l1 = lg[i1], l2 = lg[i2];
    float m = fmaxf(l1, l2);
    float p1 = __expf(l1 - m), p2 = __expf(l2 - m);
    float s = p1 + p2;
    ids[2*t] = i1; ids[2*t+1] = i2;
    wts[2*t] = p1 / s; wts[2*t+1] = p2 / s;
    atomicAdd(&ctrl[i1], 1); atomicAdd(&ctrl[i2], 1);
  }
}

__global__ void k_offsets(int* ctrl) {
  if (threadIdx.x == 0 && blockIdx.x == 0) {
    ctrl[7] = NTOK;                 // shared expert "count"
    int o = 0;
    #pragma unroll
    for (int e = 0; e < NEXP; e++) { ctrl[8 + e] = o; o += ctrl[e]; }  // offs[7] == 8192 always
  }
}

__global__ __launch_bounds__(256) void k_build_lists(const int* __restrict__ ids, int* __restrict__ ctrl,
                                                     int* __restrict__ tok_list, int* __restrict__ tok_pos) {
  int t = blockIdx.x * 256 + threadIdx.x;
  if (t >= NTOK) return;
  #pragma unroll
  for (int j = 0; j < 2; j++) {
    int e = ids[2*t + j];
    int pos = ctrl[8 + e] + atomicAdd(&ctrl[16 + e], 1);
    tok_list[pos] = t;
    tok_pos[2*t + j] = pos;
  }
  tok_list[ROWS_ROUTED + t] = t;    // identity list for shared expert
}

// ---------------- grouped GEMM, 128x128 tile, BK=64, 4 waves, 16x16x32 bf16 MFMA
// LDS k-chunk XOR swizzle: LDS slot s of row r holds global 16B-chunk (s ^ (r&7));
// fragment for chunk c of row r reads slot c ^ (r&7) -> 2-way banks (free, m136).
// MODE 0: u  = gather(x) @ WupT  + bup          (A rows gathered via tok_list)
// MODE 1: g  = silu(u @ WgateT + bgate) * u     (A = u packed rows; epilogue reads u)
// MODE 2: eo = g @ WdownT + bdown               (A = g packed rows)
template<int MODE>
__global__ __launch_bounds__(256) void k_moe_gemm(
    const unsigned short* __restrict__ Abase,
    const unsigned short* __restrict__ WT,    // [8][N=2048][K=2048] bf16 (pre-transposed, z<7 routed, z=7 shared)
    const float* __restrict__ biasR,          // [7][2048]
    const float* __restrict__ biasS,          // [2048]
    const int* __restrict__ ctrl,
    const int* __restrict__ tok_list,
    const unsigned short* __restrict__ Uep,   // u (MODE 1 only)
    unsigned short* __restrict__ Out)         // bf16 [ROWS_PAD][2048]
{
  const int e   = blockIdx.z;
  const int cnt = ctrl[e];
  const int m0  = blockIdx.y * 128;
  if (m0 >= cnt) return;
  const int off = ctrl[8 + e];
  const int n0  = blockIdx.x * 128;

  const unsigned short* W = WT + (size_t)e * HD * HD;
  const float* bias = (e < NROUTED) ? (biasR + e * HD) : biasS;

  __shared__ __align__(16) unsigned short As[128 * 64];   // 16 KB
  __shared__ __align__(16) unsigned short Bs[128 * 64];   // 16 KB

  const int tid  = threadIdx.x;
  const int lane = tid & 63;
  const int wid  = tid >> 6;

  // staging: 4 rounds of 32 rows; thread covers row (tid>>3)+32r, chunk slot tid&7.
  const int srow   = tid >> 3;               // 0..31
  const int gchunk = (tid & 7) ^ (srow & 7); // global chunk this lane fetches (XOR swizzle)
  const int skel   = gchunk * 8;             // element offset within 64-elem row

  size_t ga[4];
  #pragma unroll
  for (int r = 0; r < 4; r++) {
    int ar = m0 + srow + 32 * r;
    if (MODE == 0) {
      int tkn = tok_list[off + (ar < cnt ? ar : cnt - 1)];
      ga[r] = (size_t)tkn * HD;
    } else {
      ga[r] = (size_t)(off + ar) * HD;
    }
  }
  const unsigned short* pA[4];
  const unsigned short* pB[4];
  #pragma unroll
  for (int r = 0; r < 4; r++) {
    pA[r] = Abase + ga[r] + skel;
    pB[r] = W + (size_t)(n0 + srow + 32 * r) * HD + skel;
  }

  // LDS wave bases: round r, wave w covers rows [32r+8w, 32r+8w+8)
  unsigned short* lA[4]; unsigned short* lB[4];
  #pragma unroll
  for (int r = 0; r < 4; r++) {
    lA[r] = As + (32 * r + 8 * wid) * 64;
    lB[r] = Bs + (32 * r + 8 * wid) * 64;
  }

  const int wm = (wid >> 1) * 64;
  const int wn = (wid & 1) * 64;
  const int rm = lane & 15;
  const int cquad = lane >> 4;       // base chunk index 0..3
  const int rx = rm & 7;             // row&7 for all fragment rows

  f32x4 zero = {0.f, 0.f, 0.f, 0.f};
  f32x4 acc[4][4];
  #pragma unroll
  for (int i = 0; i < 4; i++)
    #pragma unroll
    for (int j = 0; j < 4; j++) acc[i][j] = zero;

  for (int k0 = 0; k0 < HD; k0 += 64) {
    __syncthreads();                     // previous iter's LDS reads done
    #pragma unroll
    for (int r = 0; r < 4; r++) { async16(pA[r], lA[r]); async16(pB[r], lB[r]); }
    #pragma unroll
    for (int r = 0; r < 4; r++) { pA[r] += 64; pB[r] += 64; }
    __syncthreads();                     // drains vmcnt: LDS tiles ready
    #pragma unroll
    for (int kg = 0; kg < 2; kg++) {
      const int slot = ((cquad + 4 * kg) ^ rx) * 8;   // element offset of swizzled chunk
      bf16x8 af[4], bfr[4];
      #pragma unroll
      for (int mi = 0; mi < 4; mi++) af[mi]  = *(const bf16x8*)(As + (wm + mi*16 + rm) * 64 + slot);
      #pragma unroll
      for (int ni = 0; ni < 4; ni++) bfr[ni] = *(const bf16x8*)(Bs + (wn + ni*16 + rm) * 64 + slot);
      #pragma unroll
      for (int mi = 0; mi < 4; mi++)
        #pragma unroll
        for (int ni = 0; ni < 4; ni++)
          acc[mi][ni] = __builtin_amdgcn_mfma_f32_16x16x32_bf16(af[mi], bfr[ni], acc[mi][ni], 0, 0, 0);
    }
  }

  // epilogue: C/D layout col=lane&15, row=(lane>>4)*4+reg  [verified m89/m91]
  const int quad = lane >> 4;
  #pragma unroll
  for (int mi = 0; mi < 4; mi++) {
    int rb = wm + mi * 16 + quad * 4;
    #pragma unroll
    for (int r = 0; r < 4; r++) {
      int gm = m0 + rb + r;
      if (gm < cnt) {
        size_t orow = (size_t)(off + gm) * HD;
        #pragma unroll
        for (int ni = 0; ni < 4; ni++) {
          int gn = n0 + wn + ni * 16 + rm;
          float v = acc[mi][ni][r] + bias[gn];
          if (MODE == 1) {
            float uv = bf2f(Uep[orow + gn]);
            float sg = v / (1.f + __expf(-v));   // silu
            v = sg * uv;
          }
          Out[orow + gn] = f2bf(v);
        }
      }
    }
  }
}

// ---------------- combine: out[t] = w0*eo[p0] + w1*eo[p1] + eo[8192+t]
__global__ __launch_bounds__(256) void k_combine(const unsigned short* __restrict__ eo,
                                                 const int* __restrict__ tok_pos,
                                                 const float* __restrict__ wts,
                                                 float* __restrict__ out) {
  int t = blockIdx.x;
  int h = threadIdx.x * 8;
  int p0 = tok_pos[2*t], p1 = tok_pos[2*t+1];
  float w0 = wts[2*t], w1 = wts[2*t+1];
  u16x8 a = *(const u16x8*)(eo + (size_t)p0 * HD + h);
  u16x8 b = *(const u16x8*)(eo + (size_t)p1 * HD + h);
  u16x8 c = *(const u16x8*)(eo + (size_t)(ROWS_ROUTED + t) * HD + h);
  float* o = out + (size_t)t * HD + h;
  #pragma unroll
  for (int i = 0; i < 8; i++) o[i] = w0 * bf2f(a[i]) + w1 * bf2f(b[i]) + bf2f(c[i]);
}

extern "C" void kernel_launch(void* const* d_in, const int* in_sizes, int n_in,
                              void* d_out, int out_size, void* d_ws, size_t ws_size,
                              hipStream_t stream) {
  (void)in_sizes; (void)n_in; (void)out_size; (void)ws_size;
  const float* x     = (const float*)d_in[0];
  const float* Wr    = (const float*)d_in[1];
  const float* br    = (const float*)d_in[2];
  const float* gbias = (const float*)d_in[3];
  const float* Wup   = (const float*)d_in[4];
  const float* bup   = (const float*)d_in[5];
  const float* Wgate = (const float*)d_in[6];
  const float* bgate = (const float*)d_in[7];
  const float* Wdown = (const float*)d_in[8];
  const float* bdown = (const float*)d_in[9];
  const float* Wsu   = (const float*)d_in[10];
  const float* bsu   = (const float*)d_in[11];
  const float* Wsg   = (const float*)d_in[12];
  const float* bsg   = (const float*)d_in[13];
  const float* Wsd   = (const float*)d_in[14];
  const float* bsd   = (const float*)d_in[15];
  float* out = (float*)d_out;

  char* ws = (char*)d_ws;
  size_t o = 0;
  auto alloc = [&](size_t bytes) { char* p = ws + o; o += (bytes + 255) & ~(size_t)255; return p; };
  unsigned short* WT   = (unsigned short*)alloc((size_t)8 * HD * HD * 2);  // [8] matrices, reused per stage
  unsigned short* xbf  = (unsigned short*)alloc((size_t)NTOK * HD * 2);
  unsigned short* bufU = (unsigned short*)alloc((size_t)ROWS_PAD * HD * 2); // u, later eo
  unsigned short* bufG = (unsigned short*)alloc((size_t)ROWS_PAD * HD * 2); // g
  int*   ctrl     = (int*)alloc(4096);
  int*   ids      = (int*)alloc(NTOK * 2 * 4);
  float* wts      = (float*)alloc(NTOK * 2 * 4);
  int*   tok_list = (int*)alloc(ROWS_TOTAL * 4);
  int*   tok_pos  = (int*)alloc(NTOK * 2 * 4);
  // total ~186 MB

  hipMemsetAsync(ctrl, 0, 96, stream);
  k_convert_bf16<<<NTOK * HD / 1024, 256, 0, stream>>>(x, xbf, NTOK * HD);
  k_router<<<NTOK / 4, 256, 0, stream>>>(x, Wr, br, gbias, ids, wts, ctrl);
  k_offsets<<<1, 64, 0, stream>>>(ctrl);
  k_build_lists<<<NTOK / 256, 256, 0, stream>>>(ids, ctrl, tok_list, tok_pos);

  dim3 tgrid(HD / 64, HD / 64, 8);
  dim3 ggrid(HD / 128, 32, 8);

  k_transpose8<<<tgrid, 256, 0, stream>>>(Wup, Wsu, WT);
  k_moe_gemm<0><<<ggrid, 256, 0, stream>>>(xbf, WT, bup, bsu, ctrl, tok_list, nullptr, bufU);

  k_transpose8<<<tgrid, 256, 0, stream>>>(Wgate, Wsg, WT);
  k_moe_gemm<1><<<ggrid, 256, 0, stream>>>(bufU, WT, bgate, bsg, ctrl, tok_list, bufU, bufG);

  k_transpose8<<<tgrid, 256, 0, stream>>>(Wdown, Wsd, WT);
  k_moe_gemm<2><<<ggrid, 256, 0, stream>>>(bufG, WT, bdown, bsd, ctrl, tok_list, nullptr, bufU);

  k_combine<<<NTOK, 256, 0, stream>>>(bufU, tok_pos, wts, out);
}